// Round 8
// baseline (138.166 us; speedup 1.0000x reference)
//
#include <hip/hip_runtime.h>

typedef unsigned short u16;
typedef unsigned int u32;
typedef __bf16 b16x8 __attribute__((ext_vector_type(8)));
typedef float f32x16 __attribute__((ext_vector_type(16)));

#define SEQ   16384
#define DM    2048
#define KT    50
#define NST   48
#define NSP   49

// involution: swap rows 4-7 <-> 8-11 within each 16-block
__device__ __forceinline__ int perm64(int g){
  int q = (g>>2)&3;
  return (q==1 || q==2) ? (g^12) : g;
}
__device__ __forceinline__ u16 bfb(float f){
  __bf16 b = (__bf16)f;
  return __builtin_bit_cast(u16, b);
}
__device__ __forceinline__ int pk2(float a, float b){
  return (int)((u32)bfb(a) | ((u32)bfb(b) << 16));
}
__device__ __forceinline__ b16x8 cast8(int4 v){ return __builtin_bit_cast(b16x8, v); }

__device__ __forceinline__ f32x16 mfma_(b16x8 a, b16x8 b, f32x16 c){
  return __builtin_amdgcn_mfma_f32_32x32x16_bf16(a, b, c, 0, 0, 0);
}

// acc = A * B   (64x64x64, A-frags [mi][kt], B-frags [kt][ni])
__device__ __forceinline__ void mm64(const b16x8 A[2][4], const b16x8 B[4][2], f32x16 acc[2][2]){
#pragma unroll
  for (int mi=0; mi<2; ++mi)
#pragma unroll
    for (int ni=0; ni<2; ++ni){
      f32x16 a;
#pragma unroll
      for (int q=0;q<16;q++) a[q] = 0.0f;
#pragma unroll
      for (int kt=0; kt<4; ++kt) a = mfma_(A[mi][kt], B[kt][ni], a);
      acc[mi][ni] = a;
    }
}

// acc (C/D layout) -> B-frags of the next matmul (B_phys = Pi * ACC, in-lane).
__device__ __forceinline__ void repack(const f32x16 acc[2][2], b16x8 B[4][2]){
#pragma unroll
  for (int kb=0; kb<4; ++kb){
    const int mi = kb>>1, t = kb&1;
#pragma unroll
    for (int ni=0; ni<2; ++ni){
      int4 dw;
      dw.x = pk2(acc[mi][ni][8*t+0], acc[mi][ni][8*t+1]);
      dw.y = pk2(acc[mi][ni][8*t+2], acc[mi][ni][8*t+3]);
      dw.z = pk2(acc[mi][ni][8*t+4], acc[mi][ni][8*t+5]);
      dw.w = pk2(acc[mi][ni][8*t+6], acc[mi][ni][8*t+7]);
      B[kb][ni] = cast8(dw);
    }
  }
}
__device__ __forceinline__ void repack_s(const f32x16 acc[2][2], b16x8 B[4][2], float s){
#pragma unroll
  for (int kb=0; kb<4; ++kb){
    const int mi = kb>>1, t = kb&1;
#pragma unroll
    for (int ni=0; ni<2; ++ni){
      int4 dw;
      dw.x = pk2(acc[mi][ni][8*t+0]*s, acc[mi][ni][8*t+1]*s);
      dw.y = pk2(acc[mi][ni][8*t+2]*s, acc[mi][ni][8*t+3]*s);
      dw.z = pk2(acc[mi][ni][8*t+4]*s, acc[mi][ni][8*t+5]*s);
      dw.w = pk2(acc[mi][ni][8*t+6]*s, acc[mi][ni][8*t+7]*s);
      B[kb][ni] = cast8(dw);
    }
  }
}

// B-frags of identity (PERM=0) or of the Pi permutation matrix (PERM=1)
template<int PERM>
__device__ __forceinline__ void ident_frags(b16x8 B[4][2], int lane){
  const int h = lane>>5, j0 = lane&31;
#pragma unroll
  for (int kt=0; kt<4; ++kt)
#pragma unroll
    for (int ni=0; ni<2; ++ni){
      const int col = j0 + 32*ni;
      int d[4];
#pragma unroll
      for (int dd=0; dd<4; ++dd){
        int r0 = 16*kt + 8*h + 2*dd, r1 = r0 + 1;
        int p0 = PERM ? perm64(r0) : r0;
        int p1 = PERM ? perm64(r1) : r1;
        d[dd] = (int)((p0==col ? 0x3F80u : 0u) | ((p1==col ? 0x3F80u : 0u) << 16));
      }
      int4 v; v.x=d[0]; v.y=d[1]; v.z=d[2]; v.w=d[3];
      B[kt][ni] = cast8(v);
    }
}

__device__ __forceinline__ float acc_wave_max(const f32x16 acc[2][2]){
  float m = 0.0f;
#pragma unroll
  for (int mi=0;mi<2;mi++)
#pragma unroll
    for (int ni=0;ni<2;ni++)
#pragma unroll
      for (int q=0;q<16;q++) m = fmaxf(m, acc[mi][ni][q]);
#pragma unroll
  for (int o=32;o>=1;o>>=1) m = fmaxf(m, __shfl_xor(m, o, 64));
  return m;
}

// S_stored = Pi^PROW * ACC * Pi^PCOL  (LDS variant XOR-swizzles cols)
template<int PROW, int PCOL>
__device__ __forceinline__ void store_mat_lds(u16* mat, const f32x16 acc[2][2], float inv, int lane){
  const int h = lane>>5, j0 = lane&31;
#pragma unroll
  for (int mi=0;mi<2;mi++)
#pragma unroll
    for (int ni=0;ni<2;ni++)
#pragma unroll
      for (int r=0;r<16;r++){
        int gp = 32*mi + (r&3) + 8*(r>>2) + 4*h;
        int a = PROW ? perm64(gp) : gp;
        int cc = 32*ni + j0;
        int b = PCOL ? perm64(cc) : cc;
        mat[a*64 + (b ^ ((a&7)<<3))] = bfb(acc[mi][ni][r]*inv);
      }
}
template<int PROW, int PCOL>
__device__ __forceinline__ void store_mat_glob(u16* mat, const f32x16 acc[2][2], float inv, int lane){
  const int h = lane>>5, j0 = lane&31;
#pragma unroll
  for (int mi=0;mi<2;mi++)
#pragma unroll
    for (int ni=0;ni<2;ni++)
#pragma unroll
      for (int r=0;r<16;r++){
        int gp = 32*mi + (r&3) + 8*(r>>2) + 4*h;
        int a = PROW ? perm64(gp) : gp;
        int cc = 32*ni + j0;
        int b = PCOL ? perm64(cc) : cc;
        mat[a*64 + b] = bfb(acc[mi][ni][r]*inv);
      }
}
__device__ __forceinline__ void load_afrag_lds(const u16* mat, b16x8 A[2][4], int lane){
  const int h = lane>>5, i0 = lane&31;
#pragma unroll
  for (int mi=0;mi<2;mi++)
#pragma unroll
    for (int kt=0;kt<4;kt++){
      int i = 32*mi + i0;
      int cb = (16*kt + 8*h) ^ ((i&7)<<3);
      A[mi][kt] = cast8(*(const int4*)(mat + i*64 + cb));
    }
}
__device__ __forceinline__ void load_afrag_glob(const u16* mat, b16x8 A[2][4], int lane){
  const int h = lane>>5, i0 = lane&31;
#pragma unroll
  for (int mi=0;mi<2;mi++)
#pragma unroll
    for (int kt=0;kt<4;kt++){
      int i = 32*mi + i0;
      A[mi][kt] = cast8(*(const int4*)(mat + i*64 + 16*kt + 8*h));
    }
}

// ============ kernel 1: fused GEMM + gold partials + 32-step chunk scan ======
// 512 blocks x 512 thr (2 blocks/CU); block b owns timesteps [32b, 32b+32).
// Waves: kq = w>>1 (kt quarter), ch = w&1 (output col half).
__global__ __launch_bounds__(512, 4) void k_fused(const float* __restrict__ in,
      const int* __restrict__ tags, const float* __restrict__ W,
      const float* __restrict__ bias, const float* __restrict__ T,
      float* __restrict__ gpart, u16* __restrict__ M1, float* __restrict__ S1){
  __shared__ __align__(16) char smem[49664];
  u16* const bA = (u16*)smem;              // [2][32*128] swizzled (16 KB)
  u16* const bB = (u16*)(smem + 16384);    // [2][64*128] swizzled (32 KB)
  __shared__ float logs_l[8];
  const int t = threadIdx.x;
  const int w = t>>6, lane = t&63;
  const int j0 = lane&31, h = lane>>5;
  const int kq = w>>1, ch = w&1;
  const int row0 = blockIdx.x*32;
  const int aswz = (j0&7)<<3;

  float rA[8], rB[2][8];
  f32x16 acc;
#pragma unroll
  for (int q=0;q<16;q++) acc[q]=0.f;

#define LOADCHUNK(kc)                                                       \
  { int r=t>>4, c8=t&15;                                                    \
    const float* p = in + (size_t)(row0+r)*DM + (kc)*128 + c8*8;            \
    float4 f0=*(const float4*)p, f1=*(const float4*)(p+4);                  \
    rA[0]=f0.x; rA[1]=f0.y; rA[2]=f0.z; rA[3]=f0.w;                         \
    rA[4]=f1.x; rA[5]=f1.y; rA[6]=f1.z; rA[7]=f1.w;                         \
    _Pragma("unroll")                                                       \
    for (int i=0;i<2;i++){                                                  \
      int g=(i<<9)+t; int rr=g>>4, cc8=g&15;                                \
      if (rr < KT){                                                         \
        const float* q2 = W + (size_t)rr*DM + (kc)*128 + cc8*8;             \
        float4 g0=*(const float4*)q2, g1=*(const float4*)(q2+4);            \
        rB[i][0]=g0.x; rB[i][1]=g0.y; rB[i][2]=g0.z; rB[i][3]=g0.w;         \
        rB[i][4]=g1.x; rB[i][5]=g1.y; rB[i][6]=g1.z; rB[i][7]=g1.w;         \
      } else {                                                              \
        _Pragma("unroll") for (int z=0;z<8;z++) rB[i][z]=0.f;               \
      }                                                                     \
    } }
#define WRITECHUNK(d)                                                       \
  { int r=t>>4, c8=t&15;                                                    \
    int offA = r*128 + ((c8*8) ^ ((r&7)<<3));                               \
    int4 da; da.x=pk2(rA[0],rA[1]); da.y=pk2(rA[2],rA[3]);                  \
    da.z=pk2(rA[4],rA[5]); da.w=pk2(rA[6],rA[7]);                           \
    *(int4*)(bA + (d)*4096 + offA) = da;                                    \
    _Pragma("unroll")                                                       \
    for (int i=0;i<2;i++){                                                  \
      int g=(i<<9)+t; int rr=g>>4, cc8=g&15;                                \
      int off = rr*128 + ((cc8*8) ^ ((rr&7)<<3));                           \
      int4 db; db.x=pk2(rB[i][0],rB[i][1]); db.y=pk2(rB[i][2],rB[i][3]);    \
      db.z=pk2(rB[i][4],rB[i][5]); db.w=pk2(rB[i][6],rB[i][7]);             \
      *(int4*)(bB + (d)*8192 + off) = db;                                   \
    } }

  LOADCHUNK(0); WRITECHUNK(0);
  __syncthreads();
  for (int kc=0; kc<16; ++kc){
    const int d = kc & 1;
    if (kc < 15) LOADCHUNK(kc+1);
    const u16* Arow = bA + d*4096 + j0*128;
    const u16* Brow = bB + d*8192 + (32*ch + j0)*128;
#pragma unroll
    for (int kk=0;kk<2;kk++){
      const int kt = kq*2 + kk;
      b16x8 aF = cast8(*(const int4*)(Arow + ((kt*16 + h*8) ^ aswz)));
      b16x8 bF = cast8(*(const int4*)(Brow + ((kt*16 + h*8) ^ aswz)));
      acc = mfma_(aF, bF, acc);
    }
    if (kc < 15) WRITECHUNK(d^1);
    __syncthreads();
  }
#undef LOADCHUNK
#undef WRITECHUNK

  // ---- epilogue: planes -> tile -> mrow/gold -> ue --------------------------
  float* planes = (float*)smem;            // [4][32][64] f32 (32 KB, over bA+bB[0])
  float* tile   = (float*)(smem + 32768);  // [32][66] f32 (8448 B, over bB[1])
  float* mrow   = (float*)(smem + 41216);  // [32]
  float* ue     = (float*)(smem + 41344);  // [32][64] f32 (8 KB)
  u16*   tmats  = (u16*)  smem;            // [4][4096] u16 (32 KB; tree only, planes dead)
#pragma unroll
  for (int r=0;r<16;r++){
    int gp = (r&3) + 8*(r>>2) + 4*h;
    planes[kq*2048 + gp*64 + 32*ch + j0] = acc[r];
  }
  // E' rows in f32 regs: E32[mi][kt][j] = E'[32mi+perm(j0)][16kt+8h+j]
  float E32[2][4][8];
  {
    const int pr = perm64(j0);
#pragma unroll
    for (int mi=0;mi<2;mi++){
      const int prow = 32*mi + pr;
#pragma unroll
      for (int kt=0;kt<4;kt++)
#pragma unroll
        for (int j=0;j<8;j++){
          const int c = 16*kt + 8*h + j;
          E32[mi][kt][j] = (prow < KT && c < KT) ? __expf(T[prow*50 + c]) : 0.f;
        }
    }
  }
  __syncthreads();
  for (int cidx = t; cidx < 2048; cidx += 512){
    int g = cidx>>6, c = cidx&63;
    float v = planes[cidx] + planes[2048+cidx] + planes[4096+cidx] + planes[6144+cidx];
    tile[g*66 + c] = (c<KT) ? (v + bias[c]) : -1e4f;
  }
  __syncthreads();
  if (t < 32){
    int g = t;
    float mx = -1e30f;
    for (int c=0;c<KT;c++) mx = fmaxf(mx, tile[g*66+c]);
    mrow[g] = mx;
    int tt = row0 + g;
    int s1 = tags[tt];
    int s0 = (tt==0) ? NST : tags[tt-1];
    float part = (tile[g*66 + s1] - mx) + T[s1*50 + s0];
    if (tt == SEQ-1) part += T[NSP*50 + s1];
#pragma unroll
    for (int o=16;o>=1;o>>=1) part += __shfl_xor(part, o, 64);
    if (t==0) gpart[blockIdx.x] = part;
  }
  __syncthreads();
  for (int cidx = t; cidx < 2048; cidx += 512){
    int g = cidx>>6, c = cidx&63;
    ue[cidx] = __expf(tile[g*66 + c] - mrow[g]);
  }
  __syncthreads();

  // ---- scan: wave w, 4 steps on rows [4w, 4w+4); u folded into A ------------
  b16x8 Bf[4][2];
  ident_frags<0>(Bf, lane);
  f32x16 sacc[2][2];
  {
    const int pr = perm64(j0);
    const int tr0 = w*4;
#pragma unroll 1
    for (int s=0;s<4;s++){
      float u0 = ue[(tr0+s)*64 + pr];
      float u1 = ue[(tr0+s)*64 + 32 + pr];
      b16x8 Af[2][4];
#pragma unroll
      for (int mi=0;mi<2;mi++){
        const float uu = mi ? u1 : u0;
#pragma unroll
        for (int kt=0;kt<4;kt++){
          int4 dw;
          dw.x = pk2(uu*E32[mi][kt][0], uu*E32[mi][kt][1]);
          dw.y = pk2(uu*E32[mi][kt][2], uu*E32[mi][kt][3]);
          dw.z = pk2(uu*E32[mi][kt][4], uu*E32[mi][kt][5]);
          dw.w = pk2(uu*E32[mi][kt][6], uu*E32[mi][kt][7]);
          Af[mi][kt] = cast8(dw);
        }
      }
      mm64(Af, Bf, sacc);
      repack(sacc, Bf);
    }
  }
  // ---- pairwise wave tree 8->1 (invariant: ACC = Pi * X) --------------------
  float m = acc_wave_max(sacc);
  float sl = __logf(m);
  float inv = 1.0f/m;
  int active = 1;
#pragma unroll 1
  for (int l=0; l<3; ++l){
    const int storer = active && ((w>>l)&1);
    if (active && lane==0) logs_l[w] = sl;
    if (storer){
      store_mat_lds<0,0>(tmats + (w>>(l+1))*4096, sacc, inv, lane);  // S = Pi*X_odd
    } else if (active){
      repack_s(sacc, Bf, inv);                                       // B = X_even
    }
    __syncthreads();
    if (active && !storer){
      b16x8 Am[2][4];
      load_afrag_lds(tmats + (w>>(l+1))*4096, Am, lane);
      mm64(Am, Bf, sacc);                    // ACC = Pi*X_odd*X_even
      sl += logs_l[w + (1<<l)];
      m = acc_wave_max(sacc);
      sl += __logf(m);
      inv = 1.0f/m;
    }
    if (storer) active = 0;
    __syncthreads();
  }
  if (w==0){
    store_mat_glob<1,0>(M1 + (size_t)blockIdx.x*4096, sacc, inv, lane);  // true X
    if (lane==0) S1[blockIdx.x] = sl;
  }
}

// ============ kernel 2: combine 64 mats/block -> M2[8] =======================
__global__ __launch_bounds__(512) void k_mid(const u16* __restrict__ M1,
      const float* __restrict__ S1, u16* __restrict__ M2, float* __restrict__ S2){
  const int t = threadIdx.x;
  const int w = t>>6, lane = t&63;
  const int j = blockIdx.x;
  __shared__ __align__(16) u16 mats[8][4096];
  __shared__ float logs[8];
  // stage 1: wave w chains mats [64j+8w, 64j+8w+8), 2-deep prefetch
  {
    const int base = j*64 + w*8;
    b16x8 Bc[4][2]; ident_frags<1>(Bc, lane);
    f32x16 a2[2][2];
    float sl = 0.f;
    b16x8 A0[2][4], A1[2][4], A2[2][4];
    load_afrag_glob(M1 + (size_t)(base+0)*4096, A0, lane);
    load_afrag_glob(M1 + (size_t)(base+1)*4096, A1, lane);
#pragma unroll 1
    for (int mm=0; mm<8; mm++){
      if (mm<6) load_afrag_glob(M1 + (size_t)(base+mm+2)*4096, A2, lane);
      sl += S1[base+mm];
      mm64(A0, Bc, a2);
      repack(a2, Bc);
#pragma unroll
      for (int mi=0;mi<2;mi++)
#pragma unroll
        for (int kt=0;kt<4;kt++){ A0[mi][kt]=A1[mi][kt]; A1[mi][kt]=A2[mi][kt]; }
    }
    float mx = acc_wave_max(a2);
    sl += __logf(mx);
    store_mat_lds<0,1>(mats[w], a2, 1.0f/mx, lane);   // true matrix
    if (lane==0) logs[w] = sl;
  }
  __syncthreads();
  // stage 2: wave 0 chains the 8 wave-results
  if (w==0){
    b16x8 Bc[4][2]; ident_frags<1>(Bc, lane);
    f32x16 a2[2][2];
#pragma unroll 1
    for (int m8=0;m8<8;m8++){
      b16x8 Am[2][4];
      load_afrag_lds(mats[m8], Am, lane);
      mm64(Am, Bc, a2);
      repack(a2, Bc);
    }
    float slog = logs[0]+logs[1]+logs[2]+logs[3]+logs[4]+logs[5]+logs[6]+logs[7];
    float m2 = acc_wave_max(a2);
    slog += __logf(m2);
    store_mat_glob<0,1>(M2 + (size_t)j*4096, a2, 1.0f/m2, lane);  // true matrix
    if (lane==0) S2[j] = slog;
  }
}

// ============ kernel 3: 1 wave — chain M2[8], alpha, LSE, gold, out ==========
__global__ __launch_bounds__(64) void k_last(const u16* __restrict__ M2,
      const float* __restrict__ S2, const float* __restrict__ T,
      const float* __restrict__ gpart, float* __restrict__ out){
  const int lane = threadIdx.x & 63;
  const int h = lane>>5;
  __shared__ float alpha[64];
  float gold = 0.f;
#pragma unroll
  for (int i=0;i<8;i++) gold += gpart[lane + 64*i];
#pragma unroll
  for (int o=32;o>=1;o>>=1) gold += __shfl_xor(gold, o, 64);

  b16x8 Bc[4][2]; ident_frags<1>(Bc, lane);
  f32x16 a2[2][2];
  float slog = 0.f;
  b16x8 A0[2][4], A1[2][4], A2[2][4];
  load_afrag_glob(M2 + (size_t)0*4096, A0, lane);
  load_afrag_glob(M2 + (size_t)1*4096, A1, lane);
#pragma unroll 1
  for (int m8=0;m8<8;m8++){
    if (m8<6) load_afrag_glob(M2 + (size_t)(m8+2)*4096, A2, lane);
    slog += S2[m8];
    mm64(A0, Bc, a2);
    repack(a2, Bc);
#pragma unroll
    for (int mi=0;mi<2;mi++)
#pragma unroll
      for (int kt=0;kt<4;kt++){ A0[mi][kt]=A1[mi][kt]; A1[mi][kt]=A2[mi][kt]; }
  }
  if ((lane&31)==16){   // column START=48 lives in lanes 16 / 48 (ni=1)
#pragma unroll
    for (int mi=0;mi<2;mi++)
#pragma unroll
      for (int r=0;r<16;r++){
        int gp = 32*mi + (r&3) + 8*(r>>2) + 4*h;
        alpha[gp] = a2[mi][1][r];
      }
  }
  float a = alpha[lane];
  float term = (lane < KT && a > 0.f) ? (__logf(a) + slog + T[NSP*50 + lane]) : -1e30f;
  float tm = term;
#pragma unroll
  for (int o=32;o>=1;o>>=1) tm = fmaxf(tm, __shfl_xor(tm, o, 64));
  float e = __expf(term - tm);
#pragma unroll
  for (int o=32;o>=1;o>>=1) e += __shfl_xor(e, o, 64);
  if (lane==0) out[0] = (tm + __logf(e)) - gold;
}

extern "C" void kernel_launch(void* const* d_in, const int* in_sizes, int n_in,
                              void* d_out, int out_size, void* d_ws, size_t ws_size,
                              hipStream_t stream) {
  (void)in_sizes; (void)n_in; (void)out_size; (void)ws_size;
  const float* input = (const float*)d_in[0];
  const int*   tags  = (const int*)  d_in[1];
  const float* W     = (const float*)d_in[2];
  const float* bias  = (const float*)d_in[3];
  const float* T     = (const float*)d_in[4];

  char* ws = (char*)d_ws;
  float* gpart = (float*)(ws + 0);        // 512*4      = 2048
  u16*   M1    = (u16*)  (ws + 2048);     // 512*4096*2 = 4194304
  float* S1    = (float*)(ws + 4196352);  // 512*4      = 2048
  u16*   M2    = (u16*)  (ws + 4198400);  // 8*4096*2   = 65536
  float* S2    = (float*)(ws + 4263936);  // 8*4

  k_fused<<<512, 512, 0, stream>>>(input, tags, W, bias, T, gpart, M1, S1);
  k_mid  <<<8,   512, 0, stream>>>(M1, S1, M2, S2);
  k_last <<<1,   64,  0, stream>>>(M2, S2, T, gpart, (float*)d_out);
}

// Round 9
// 129.248 us; speedup vs baseline: 1.0690x; 1.0690x over previous
//
#include <hip/hip_runtime.h>

typedef unsigned short u16;
typedef unsigned int u32;
typedef __bf16 b16x8 __attribute__((ext_vector_type(8)));
typedef float f32x16 __attribute__((ext_vector_type(16)));

#define SEQ   16384
#define DM    2048
#define KT    50
#define NST   48
#define NSP   49

// involution: swap rows 4-7 <-> 8-11 within each 16-block
__device__ __forceinline__ int perm64(int g){
  int q = (g>>2)&3;
  return (q==1 || q==2) ? (g^12) : g;
}
__device__ __forceinline__ u16 bfb(float f){
  __bf16 b = (__bf16)f;
  return __builtin_bit_cast(u16, b);
}
__device__ __forceinline__ int pk2(float a, float b){
  return (int)((u32)bfb(a) | ((u32)bfb(b) << 16));
}
__device__ __forceinline__ b16x8 cast8(int4 v){ return __builtin_bit_cast(b16x8, v); }

__device__ __forceinline__ f32x16 mfma_(b16x8 a, b16x8 b, f32x16 c){
  return __builtin_amdgcn_mfma_f32_32x32x16_bf16(a, b, c, 0, 0, 0);
}

// acc = A * B   (64x64x64, A-frags [mi][kt], B-frags [kt][ni])
__device__ __forceinline__ void mm64(const b16x8 A[2][4], const b16x8 B[4][2], f32x16 acc[2][2]){
#pragma unroll
  for (int mi=0; mi<2; ++mi)
#pragma unroll
    for (int ni=0; ni<2; ++ni){
      f32x16 a;
#pragma unroll
      for (int q=0;q<16;q++) a[q] = 0.0f;
#pragma unroll
      for (int kt=0; kt<4; ++kt) a = mfma_(A[mi][kt], B[kt][ni], a);
      acc[mi][ni] = a;
    }
}

// acc (C/D layout) -> B-frags of the next matmul (B_phys = Pi * ACC, in-lane).
__device__ __forceinline__ void repack(const f32x16 acc[2][2], b16x8 B[4][2]){
#pragma unroll
  for (int kb=0; kb<4; ++kb){
    const int mi = kb>>1, t = kb&1;
#pragma unroll
    for (int ni=0; ni<2; ++ni){
      int4 dw;
      dw.x = pk2(acc[mi][ni][8*t+0], acc[mi][ni][8*t+1]);
      dw.y = pk2(acc[mi][ni][8*t+2], acc[mi][ni][8*t+3]);
      dw.z = pk2(acc[mi][ni][8*t+4], acc[mi][ni][8*t+5]);
      dw.w = pk2(acc[mi][ni][8*t+6], acc[mi][ni][8*t+7]);
      B[kb][ni] = cast8(dw);
    }
  }
}
__device__ __forceinline__ void repack_s(const f32x16 acc[2][2], b16x8 B[4][2], float s){
#pragma unroll
  for (int kb=0; kb<4; ++kb){
    const int mi = kb>>1, t = kb&1;
#pragma unroll
    for (int ni=0; ni<2; ++ni){
      int4 dw;
      dw.x = pk2(acc[mi][ni][8*t+0]*s, acc[mi][ni][8*t+1]*s);
      dw.y = pk2(acc[mi][ni][8*t+2]*s, acc[mi][ni][8*t+3]*s);
      dw.z = pk2(acc[mi][ni][8*t+4]*s, acc[mi][ni][8*t+5]*s);
      dw.w = pk2(acc[mi][ni][8*t+6]*s, acc[mi][ni][8*t+7]*s);
      B[kb][ni] = cast8(dw);
    }
  }
}

// B-frags of identity (PERM=0) or of the Pi permutation matrix (PERM=1)
template<int PERM>
__device__ __forceinline__ void ident_frags(b16x8 B[4][2], int lane){
  const int h = lane>>5, j0 = lane&31;
#pragma unroll
  for (int kt=0; kt<4; ++kt)
#pragma unroll
    for (int ni=0; ni<2; ++ni){
      const int col = j0 + 32*ni;
      int d[4];
#pragma unroll
      for (int dd=0; dd<4; ++dd){
        int r0 = 16*kt + 8*h + 2*dd, r1 = r0 + 1;
        int p0 = PERM ? perm64(r0) : r0;
        int p1 = PERM ? perm64(r1) : r1;
        d[dd] = (int)((p0==col ? 0x3F80u : 0u) | ((p1==col ? 0x3F80u : 0u) << 16));
      }
      int4 v; v.x=d[0]; v.y=d[1]; v.z=d[2]; v.w=d[3];
      B[kt][ni] = cast8(v);
    }
}

__device__ __forceinline__ float acc_wave_max(const f32x16 acc[2][2]){
  float m = 0.0f;
#pragma unroll
  for (int mi=0;mi<2;mi++)
#pragma unroll
    for (int ni=0;ni<2;ni++)
#pragma unroll
      for (int q=0;q<16;q++) m = fmaxf(m, acc[mi][ni][q]);
#pragma unroll
  for (int o=32;o>=1;o>>=1) m = fmaxf(m, __shfl_xor(m, o, 64));
  return m;
}

// S_stored = Pi^PROW * ACC * Pi^PCOL  (LDS variant XOR-swizzles cols)
template<int PROW, int PCOL>
__device__ __forceinline__ void store_mat_lds(u16* mat, const f32x16 acc[2][2], float inv, int lane){
  const int h = lane>>5, j0 = lane&31;
#pragma unroll
  for (int mi=0;mi<2;mi++)
#pragma unroll
    for (int ni=0;ni<2;ni++)
#pragma unroll
      for (int r=0;r<16;r++){
        int gp = 32*mi + (r&3) + 8*(r>>2) + 4*h;
        int a = PROW ? perm64(gp) : gp;
        int cc = 32*ni + j0;
        int b = PCOL ? perm64(cc) : cc;
        mat[a*64 + (b ^ ((a&7)<<3))] = bfb(acc[mi][ni][r]*inv);
      }
}
template<int PROW, int PCOL>
__device__ __forceinline__ void store_mat_glob(u16* mat, const f32x16 acc[2][2], float inv, int lane){
  const int h = lane>>5, j0 = lane&31;
#pragma unroll
  for (int mi=0;mi<2;mi++)
#pragma unroll
    for (int ni=0;ni<2;ni++)
#pragma unroll
      for (int r=0;r<16;r++){
        int gp = 32*mi + (r&3) + 8*(r>>2) + 4*h;
        int a = PROW ? perm64(gp) : gp;
        int cc = 32*ni + j0;
        int b = PCOL ? perm64(cc) : cc;
        mat[a*64 + b] = bfb(acc[mi][ni][r]*inv);
      }
}
__device__ __forceinline__ void load_afrag_lds(const u16* mat, b16x8 A[2][4], int lane){
  const int h = lane>>5, i0 = lane&31;
#pragma unroll
  for (int mi=0;mi<2;mi++)
#pragma unroll
    for (int kt=0;kt<4;kt++){
      int i = 32*mi + i0;
      int cb = (16*kt + 8*h) ^ ((i&7)<<3);
      A[mi][kt] = cast8(*(const int4*)(mat + i*64 + cb));
    }
}
__device__ __forceinline__ void load_afrag_glob(const u16* mat, b16x8 A[2][4], int lane){
  const int h = lane>>5, i0 = lane&31;
#pragma unroll
  for (int mi=0;mi<2;mi++)
#pragma unroll
    for (int kt=0;kt<4;kt++){
      int i = 32*mi + i0;
      A[mi][kt] = cast8(*(const int4*)(mat + i*64 + 16*kt + 8*h));
    }
}

// ============ kernel 1: fused GEMM + gold partials + 32-step chunk scan ======
// 512 blocks x 512 thr; launch_bounds(512,2) -> VGPR cap 128 (no spill),
// 2 blocks/CU co-resident (LDS 48.5 KB x2 = 97 KB < 160 KB).
__global__ __launch_bounds__(512, 2) void k_fused(const float* __restrict__ in,
      const int* __restrict__ tags, const float* __restrict__ W,
      const float* __restrict__ bias, const float* __restrict__ T,
      float* __restrict__ gpart, u16* __restrict__ M1, float* __restrict__ S1){
  __shared__ __align__(16) char smem[49664];
  u16* const bA = (u16*)smem;              // [2][32*128] swizzled (16 KB)
  u16* const bB = (u16*)(smem + 16384);    // [2][64*128] swizzled (32 KB)
  __shared__ float logs_l[8];
  const int t = threadIdx.x;
  const int w = t>>6, lane = t&63;
  const int j0 = lane&31, h = lane>>5;
  const int kq = w>>1, ch = w&1;
  const int row0 = blockIdx.x*32;
  const int aswz = (j0&7)<<3;

  float rA[8], rB[2][8];
  f32x16 acc;
#pragma unroll
  for (int q=0;q<16;q++) acc[q]=0.f;

#define LOADCHUNK(kc)                                                       \
  { int r=t>>4, c8=t&15;                                                    \
    const float* p = in + (size_t)(row0+r)*DM + (kc)*128 + c8*8;            \
    float4 f0=*(const float4*)p, f1=*(const float4*)(p+4);                  \
    rA[0]=f0.x; rA[1]=f0.y; rA[2]=f0.z; rA[3]=f0.w;                         \
    rA[4]=f1.x; rA[5]=f1.y; rA[6]=f1.z; rA[7]=f1.w;                         \
    _Pragma("unroll")                                                       \
    for (int i=0;i<2;i++){                                                  \
      int g=(i<<9)+t; int rr=g>>4, cc8=g&15;                                \
      if (rr < KT){                                                         \
        const float* q2 = W + (size_t)rr*DM + (kc)*128 + cc8*8;             \
        float4 g0=*(const float4*)q2, g1=*(const float4*)(q2+4);            \
        rB[i][0]=g0.x; rB[i][1]=g0.y; rB[i][2]=g0.z; rB[i][3]=g0.w;         \
        rB[i][4]=g1.x; rB[i][5]=g1.y; rB[i][6]=g1.z; rB[i][7]=g1.w;         \
      } else {                                                              \
        _Pragma("unroll") for (int z=0;z<8;z++) rB[i][z]=0.f;               \
      }                                                                     \
    } }
#define WRITECHUNK(d)                                                       \
  { int r=t>>4, c8=t&15;                                                    \
    int offA = r*128 + ((c8*8) ^ ((r&7)<<3));                               \
    int4 da; da.x=pk2(rA[0],rA[1]); da.y=pk2(rA[2],rA[3]);                  \
    da.z=pk2(rA[4],rA[5]); da.w=pk2(rA[6],rA[7]);                           \
    *(int4*)(bA + (d)*4096 + offA) = da;                                    \
    _Pragma("unroll")                                                       \
    for (int i=0;i<2;i++){                                                  \
      int g=(i<<9)+t; int rr=g>>4, cc8=g&15;                                \
      int off = rr*128 + ((cc8*8) ^ ((rr&7)<<3));                           \
      int4 db; db.x=pk2(rB[i][0],rB[i][1]); db.y=pk2(rB[i][2],rB[i][3]);    \
      db.z=pk2(rB[i][4],rB[i][5]); db.w=pk2(rB[i][6],rB[i][7]);             \
      *(int4*)(bB + (d)*8192 + off) = db;                                   \
    } }

  LOADCHUNK(0); WRITECHUNK(0);
  __syncthreads();
  for (int kc=0; kc<16; ++kc){
    const int d = kc & 1;
    if (kc < 15) LOADCHUNK(kc+1);
    const u16* Arow = bA + d*4096 + j0*128;
    const u16* Brow = bB + d*8192 + (32*ch + j0)*128;
#pragma unroll
    for (int kk=0;kk<2;kk++){
      const int kt = kq*2 + kk;
      b16x8 aF = cast8(*(const int4*)(Arow + ((kt*16 + h*8) ^ aswz)));
      b16x8 bF = cast8(*(const int4*)(Brow + ((kt*16 + h*8) ^ aswz)));
      acc = mfma_(aF, bF, acc);
    }
    if (kc < 15) WRITECHUNK(d^1);
    __syncthreads();
  }
#undef LOADCHUNK
#undef WRITECHUNK

  // ---- epilogue: planes -> tile -> mrow/gold -> ue --------------------------
  float* planes = (float*)smem;            // [4][32][64] f32 (32 KB, over bA+bB[0])
  float* tile   = (float*)(smem + 32768);  // [32][66] f32 (8448 B, over bB[1])
  float* mrow   = (float*)(smem + 41216);  // [32]
  float* ue     = (float*)(smem + 41344);  // [32][64] f32 (8 KB)
  u16*   tmats  = (u16*)  smem;            // [4][4096] u16 (32 KB; tree only, planes dead)
#pragma unroll
  for (int r=0;r<16;r++){
    int gp = (r&3) + 8*(r>>2) + 4*h;
    planes[kq*2048 + gp*64 + 32*ch + j0] = acc[r];
  }
  // E' rows in f32 regs: E32[mi][kt][j] = E'[32mi+perm(j0)][16kt+8h+j]
  float E32[2][4][8];
  {
    const int pr = perm64(j0);
#pragma unroll
    for (int mi=0;mi<2;mi++){
      const int prow = 32*mi + pr;
#pragma unroll
      for (int kt=0;kt<4;kt++)
#pragma unroll
        for (int j=0;j<8;j++){
          const int c = 16*kt + 8*h + j;
          E32[mi][kt][j] = (prow < KT && c < KT) ? __expf(T[prow*50 + c]) : 0.f;
        }
    }
  }
  __syncthreads();
  for (int cidx = t; cidx < 2048; cidx += 512){
    int g = cidx>>6, c = cidx&63;
    float v = planes[cidx] + planes[2048+cidx] + planes[4096+cidx] + planes[6144+cidx];
    tile[g*66 + c] = (c<KT) ? (v + bias[c]) : -1e4f;
  }
  __syncthreads();
  if (t < 32){
    int g = t;
    float mx = -1e30f;
    for (int c=0;c<KT;c++) mx = fmaxf(mx, tile[g*66+c]);
    mrow[g] = mx;
    int tt = row0 + g;
    int s1 = tags[tt];
    int s0 = (tt==0) ? NST : tags[tt-1];
    float part = (tile[g*66 + s1] - mx) + T[s1*50 + s0];
    if (tt == SEQ-1) part += T[NSP*50 + s1];
#pragma unroll
    for (int o=16;o>=1;o>>=1) part += __shfl_xor(part, o, 64);
    if (t==0) gpart[blockIdx.x] = part;
  }
  __syncthreads();
  for (int cidx = t; cidx < 2048; cidx += 512){
    int g = cidx>>6, c = cidx&63;
    ue[cidx] = __expf(tile[g*66 + c] - mrow[g]);
  }
  __syncthreads();

  // ---- scan: wave w, 4 steps on rows [4w, 4w+4); u folded into A ------------
  b16x8 Bf[4][2];
  ident_frags<0>(Bf, lane);
  f32x16 sacc[2][2];
  {
    const int pr = perm64(j0);
    const int tr0 = w*4;
#pragma unroll 1
    for (int s=0;s<4;s++){
      float u0 = ue[(tr0+s)*64 + pr];
      float u1 = ue[(tr0+s)*64 + 32 + pr];
      b16x8 Af[2][4];
#pragma unroll
      for (int mi=0;mi<2;mi++){
        const float uu = mi ? u1 : u0;
#pragma unroll
        for (int kt=0;kt<4;kt++){
          int4 dw;
          dw.x = pk2(uu*E32[mi][kt][0], uu*E32[mi][kt][1]);
          dw.y = pk2(uu*E32[mi][kt][2], uu*E32[mi][kt][3]);
          dw.z = pk2(uu*E32[mi][kt][4], uu*E32[mi][kt][5]);
          dw.w = pk2(uu*E32[mi][kt][6], uu*E32[mi][kt][7]);
          Af[mi][kt] = cast8(dw);
        }
      }
      mm64(Af, Bf, sacc);
      repack(sacc, Bf);
    }
  }
  // ---- pairwise wave tree 8->1 (invariant: ACC = Pi * X) --------------------
  float m = acc_wave_max(sacc);
  float sl = __logf(m);
  float inv = 1.0f/m;
  int active = 1;
#pragma unroll 1
  for (int l=0; l<3; ++l){
    const int storer = active && ((w>>l)&1);
    if (active && lane==0) logs_l[w] = sl;
    if (storer){
      store_mat_lds<0,0>(tmats + (w>>(l+1))*4096, sacc, inv, lane);  // S = Pi*X_odd
    } else if (active){
      repack_s(sacc, Bf, inv);                                       // B = X_even
    }
    __syncthreads();
    if (active && !storer){
      b16x8 Am[2][4];
      load_afrag_lds(tmats + (w>>(l+1))*4096, Am, lane);
      mm64(Am, Bf, sacc);                    // ACC = Pi*X_odd*X_even
      sl += logs_l[w + (1<<l)];
      m = acc_wave_max(sacc);
      sl += __logf(m);
      inv = 1.0f/m;
    }
    if (storer) active = 0;
    __syncthreads();
  }
  if (w==0){
    store_mat_glob<1,0>(M1 + (size_t)blockIdx.x*4096, sacc, inv, lane);  // true X
    if (lane==0) S1[blockIdx.x] = sl;
  }
}

// ============ kernel 2: combine 64 mats/block -> M2[8] =======================
__global__ __launch_bounds__(512) void k_mid(const u16* __restrict__ M1,
      const float* __restrict__ S1, u16* __restrict__ M2, float* __restrict__ S2){
  const int t = threadIdx.x;
  const int w = t>>6, lane = t&63;
  const int j = blockIdx.x;
  __shared__ __align__(16) u16 mats[8][4096];
  __shared__ float logs[8];
  // stage 1: wave w chains mats [64j+8w, 64j+8w+8), 2-deep prefetch
  {
    const int base = j*64 + w*8;
    b16x8 Bc[4][2]; ident_frags<1>(Bc, lane);
    f32x16 a2[2][2];
    float sl = 0.f;
    b16x8 A0[2][4], A1[2][4], A2[2][4];
    load_afrag_glob(M1 + (size_t)(base+0)*4096, A0, lane);
    load_afrag_glob(M1 + (size_t)(base+1)*4096, A1, lane);
#pragma unroll 1
    for (int mm=0; mm<8; mm++){
      if (mm<6) load_afrag_glob(M1 + (size_t)(base+mm+2)*4096, A2, lane);
      sl += S1[base+mm];
      mm64(A0, Bc, a2);
      repack(a2, Bc);
#pragma unroll
      for (int mi=0;mi<2;mi++)
#pragma unroll
        for (int kt=0;kt<4;kt++){ A0[mi][kt]=A1[mi][kt]; A1[mi][kt]=A2[mi][kt]; }
    }
    float mx = acc_wave_max(a2);
    sl += __logf(mx);
    store_mat_lds<0,1>(mats[w], a2, 1.0f/mx, lane);   // true matrix
    if (lane==0) logs[w] = sl;
  }
  __syncthreads();
  // stage 2: wave 0 chains the 8 wave-results
  if (w==0){
    b16x8 Bc[4][2]; ident_frags<1>(Bc, lane);
    f32x16 a2[2][2];
#pragma unroll 1
    for (int m8=0;m8<8;m8++){
      b16x8 Am[2][4];
      load_afrag_lds(mats[m8], Am, lane);
      mm64(Am, Bc, a2);
      repack(a2, Bc);
    }
    float slog = logs[0]+logs[1]+logs[2]+logs[3]+logs[4]+logs[5]+logs[6]+logs[7];
    float m2 = acc_wave_max(a2);
    slog += __logf(m2);
    store_mat_glob<0,1>(M2 + (size_t)j*4096, a2, 1.0f/m2, lane);  // true matrix
    if (lane==0) S2[j] = slog;
  }
}

// ============ kernel 3: 1 wave — chain M2[8], alpha, LSE, gold, out ==========
__global__ __launch_bounds__(64) void k_last(const u16* __restrict__ M2,
      const float* __restrict__ S2, const float* __restrict__ T,
      const float* __restrict__ gpart, float* __restrict__ out){
  const int lane = threadIdx.x & 63;
  const int h = lane>>5;
  __shared__ float alpha[64];
  float gold = 0.f;
#pragma unroll
  for (int i=0;i<8;i++) gold += gpart[lane + 64*i];
#pragma unroll
  for (int o=32;o>=1;o>>=1) gold += __shfl_xor(gold, o, 64);

  b16x8 Bc[4][2]; ident_frags<1>(Bc, lane);
  f32x16 a2[2][2];
  float slog = 0.f;
  b16x8 A0[2][4], A1[2][4], A2[2][4];
  load_afrag_glob(M2 + (size_t)0*4096, A0, lane);
  load_afrag_glob(M2 + (size_t)1*4096, A1, lane);
#pragma unroll 1
  for (int m8=0;m8<8;m8++){
    if (m8<6) load_afrag_glob(M2 + (size_t)(m8+2)*4096, A2, lane);
    slog += S2[m8];
    mm64(A0, Bc, a2);
    repack(a2, Bc);
#pragma unroll
    for (int mi=0;mi<2;mi++)
#pragma unroll
      for (int kt=0;kt<4;kt++){ A0[mi][kt]=A1[mi][kt]; A1[mi][kt]=A2[mi][kt]; }
  }
  if ((lane&31)==16){   // column START=48 lives in lanes 16 / 48 (ni=1)
#pragma unroll
    for (int mi=0;mi<2;mi++)
#pragma unroll
      for (int r=0;r<16;r++){
        int gp = 32*mi + (r&3) + 8*(r>>2) + 4*h;
        alpha[gp] = a2[mi][1][r];
      }
  }
  float a = alpha[lane];
  float term = (lane < KT && a > 0.f) ? (__logf(a) + slog + T[NSP*50 + lane]) : -1e30f;
  float tm = term;
#pragma unroll
  for (int o=32;o>=1;o>>=1) tm = fmaxf(tm, __shfl_xor(tm, o, 64));
  float e = __expf(term - tm);
#pragma unroll
  for (int o=32;o>=1;o>>=1) e += __shfl_xor(e, o, 64);
  if (lane==0) out[0] = (tm + __logf(e)) - gold;
}

extern "C" void kernel_launch(void* const* d_in, const int* in_sizes, int n_in,
                              void* d_out, int out_size, void* d_ws, size_t ws_size,
                              hipStream_t stream) {
  (void)in_sizes; (void)n_in; (void)out_size; (void)ws_size;
  const float* input = (const float*)d_in[0];
  const int*   tags  = (const int*)  d_in[1];
  const float* W     = (const float*)d_in[2];
  const float* bias  = (const float*)d_in[3];
  const float* T     = (const float*)d_in[4];

  char* ws = (char*)d_ws;
  float* gpart = (float*)(ws + 0);        // 512*4      = 2048
  u16*   M1    = (u16*)  (ws + 2048);     // 512*4096*2 = 4194304
  float* S1    = (float*)(ws + 4196352);  // 512*4      = 2048
  u16*   M2    = (u16*)  (ws + 4198400);  // 8*4096*2   = 65536
  float* S2    = (float*)(ws + 4263936);  // 8*4

  k_fused<<<512, 512, 0, stream>>>(input, tags, W, bias, T, gpart, M1, S1);
  k_mid  <<<8,   512, 0, stream>>>(M1, S1, M2, S2);
  k_last <<<1,   64,  0, stream>>>(M2, S2, T, gpart, (float*)d_out);
}

// Round 10
// 97.512 us; speedup vs baseline: 1.4169x; 1.3255x over previous
//
#include <hip/hip_runtime.h>

typedef unsigned short u16;
typedef unsigned int u32;
typedef __bf16 b16x8 __attribute__((ext_vector_type(8)));
typedef float f32x16 __attribute__((ext_vector_type(16)));

#define SEQ   16384
#define DM    2048
#define KT    50
#define NST   48
#define NSP   49

// involution: swap rows 4-7 <-> 8-11 within each 16-block
__device__ __forceinline__ int perm64(int g){
  int q = (g>>2)&3;
  return (q==1 || q==2) ? (g^12) : g;
}
__device__ __forceinline__ u16 bfb(float f){
  __bf16 b = (__bf16)f;
  return __builtin_bit_cast(u16, b);
}
__device__ __forceinline__ int pk2(float a, float b){
  return (int)((u32)bfb(a) | ((u32)bfb(b) << 16));
}
__device__ __forceinline__ b16x8 cast8(int4 v){ return __builtin_bit_cast(b16x8, v); }

__device__ __forceinline__ f32x16 mfma_(b16x8 a, b16x8 b, f32x16 c){
  return __builtin_amdgcn_mfma_f32_32x32x16_bf16(a, b, c, 0, 0, 0);
}

// acc = A * B   (64x64x64, A-frags [mi][kt], B-frags [kt][ni])
__device__ __forceinline__ void mm64(const b16x8 A[2][4], const b16x8 B[4][2], f32x16 acc[2][2]){
#pragma unroll
  for (int mi=0; mi<2; ++mi)
#pragma unroll
    for (int ni=0; ni<2; ++ni){
      f32x16 a;
#pragma unroll
      for (int q=0;q<16;q++) a[q] = 0.0f;
#pragma unroll
      for (int kt=0; kt<4; ++kt) a = mfma_(A[mi][kt], B[kt][ni], a);
      acc[mi][ni] = a;
    }
}

// acc (C/D layout) -> B-frags of the next matmul (B_phys = Pi * ACC, in-lane).
__device__ __forceinline__ void repack(const f32x16 acc[2][2], b16x8 B[4][2]){
#pragma unroll
  for (int kb=0; kb<4; ++kb){
    const int mi = kb>>1, t = kb&1;
#pragma unroll
    for (int ni=0; ni<2; ++ni){
      int4 dw;
      dw.x = pk2(acc[mi][ni][8*t+0], acc[mi][ni][8*t+1]);
      dw.y = pk2(acc[mi][ni][8*t+2], acc[mi][ni][8*t+3]);
      dw.z = pk2(acc[mi][ni][8*t+4], acc[mi][ni][8*t+5]);
      dw.w = pk2(acc[mi][ni][8*t+6], acc[mi][ni][8*t+7]);
      B[kb][ni] = cast8(dw);
    }
  }
}
__device__ __forceinline__ void repack_s(const f32x16 acc[2][2], b16x8 B[4][2], float s){
#pragma unroll
  for (int kb=0; kb<4; ++kb){
    const int mi = kb>>1, t = kb&1;
#pragma unroll
    for (int ni=0; ni<2; ++ni){
      int4 dw;
      dw.x = pk2(acc[mi][ni][8*t+0]*s, acc[mi][ni][8*t+1]*s);
      dw.y = pk2(acc[mi][ni][8*t+2]*s, acc[mi][ni][8*t+3]*s);
      dw.z = pk2(acc[mi][ni][8*t+4]*s, acc[mi][ni][8*t+5]*s);
      dw.w = pk2(acc[mi][ni][8*t+6]*s, acc[mi][ni][8*t+7]*s);
      B[kb][ni] = cast8(dw);
    }
  }
}

// B-frags of identity (PERM=0) or of the Pi permutation matrix (PERM=1)
template<int PERM>
__device__ __forceinline__ void ident_frags(b16x8 B[4][2], int lane){
  const int h = lane>>5, j0 = lane&31;
#pragma unroll
  for (int kt=0; kt<4; ++kt)
#pragma unroll
    for (int ni=0; ni<2; ++ni){
      const int col = j0 + 32*ni;
      int d[4];
#pragma unroll
      for (int dd=0; dd<4; ++dd){
        int r0 = 16*kt + 8*h + 2*dd, r1 = r0 + 1;
        int p0 = PERM ? perm64(r0) : r0;
        int p1 = PERM ? perm64(r1) : r1;
        d[dd] = (int)((p0==col ? 0x3F80u : 0u) | ((p1==col ? 0x3F80u : 0u) << 16));
      }
      int4 v; v.x=d[0]; v.y=d[1]; v.z=d[2]; v.w=d[3];
      B[kt][ni] = cast8(v);
    }
}

__device__ __forceinline__ float acc_wave_max(const f32x16 acc[2][2]){
  float m = 0.0f;
#pragma unroll
  for (int mi=0;mi<2;mi++)
#pragma unroll
    for (int ni=0;ni<2;ni++)
#pragma unroll
      for (int q=0;q<16;q++) m = fmaxf(m, acc[mi][ni][q]);
#pragma unroll
  for (int o=32;o>=1;o>>=1) m = fmaxf(m, __shfl_xor(m, o, 64));
  return m;
}

template<int PROW>
__device__ __forceinline__ void store_mat_lds(u16* mat, const f32x16 acc[2][2], float inv, int lane){
  const int h = lane>>5, j0 = lane&31;
#pragma unroll
  for (int mi=0;mi<2;mi++)
#pragma unroll
    for (int ni=0;ni<2;ni++)
#pragma unroll
      for (int r=0;r<16;r++){
        int gp = 32*mi + (r&3) + 8*(r>>2) + 4*h;
        int a = PROW ? perm64(gp) : gp;
        int b = perm64(32*ni + j0);
        mat[a*64 + (b ^ ((a&7)<<3))] = bfb(acc[mi][ni][r]*inv);
      }
}
template<int PROW>
__device__ __forceinline__ void store_mat_glob(u16* mat, const f32x16 acc[2][2], float inv, int lane){
  const int h = lane>>5, j0 = lane&31;
#pragma unroll
  for (int mi=0;mi<2;mi++)
#pragma unroll
    for (int ni=0;ni<2;ni++)
#pragma unroll
      for (int r=0;r<16;r++){
        int gp = 32*mi + (r&3) + 8*(r>>2) + 4*h;
        int a = PROW ? perm64(gp) : gp;
        int b = perm64(32*ni + j0);
        mat[a*64 + b] = bfb(acc[mi][ni][r]*inv);
      }
}
__device__ __forceinline__ void load_afrag_lds(const u16* mat, b16x8 A[2][4], int lane){
  const int h = lane>>5, i0 = lane&31;
#pragma unroll
  for (int mi=0;mi<2;mi++)
#pragma unroll
    for (int kt=0;kt<4;kt++){
      int i = 32*mi + i0;
      int cb = (16*kt + 8*h) ^ ((i&7)<<3);
      A[mi][kt] = cast8(*(const int4*)(mat + i*64 + cb));
    }
}
__device__ __forceinline__ void load_afrag_glob(const u16* mat, b16x8 A[2][4], int lane){
  const int h = lane>>5, i0 = lane&31;
#pragma unroll
  for (int mi=0;mi<2;mi++)
#pragma unroll
    for (int kt=0;kt<4;kt++){
      int i = 32*mi + i0;
      A[mi][kt] = cast8(*(const int4*)(mat + i*64 + 16*kt + 8*h));
    }
}

// ============ kernel 1: emission GEMM from raw inputs + gold partials ========
// 256 blocks x 512 thr, 64 seq rows/block, BK=128, double-buffered LDS,
// B (=W) converted fp32->bf16 inline (W is L2-resident across blocks).
__global__ __launch_bounds__(512, 2) void k_gemm(const float* __restrict__ in,
      const int* __restrict__ tags, const float* __restrict__ W,
      const float* __restrict__ bias, const float* __restrict__ T,
      float* __restrict__ feats, float* __restrict__ gpart, int* __restrict__ counter){
  __shared__ __align__(16) char smem[65536];
  u16* const bA = (u16*)smem;              // [2][64*128] swizzled
  u16* const bB = (u16*)(smem + 32768);    // [2][64*128] swizzled
  const int t = threadIdx.x;
  const int w = t>>6, lane = t&63;
  const int j0 = lane&31, h = lane>>5;
  const int rh = w&1, ch = (w>>1)&1, kq = (w>>2)&1;
  const int row0 = blockIdx.x*64;
  const int aswz = (j0&7)<<3;
  if (blockIdx.x==0 && t==0) *counter = 0;

  float rA[2][8], rB[2][8];
  f32x16 acc;
#pragma unroll
  for (int q=0;q<16;q++) acc[q]=0.f;

#define LOADCHUNK(kc)                                                       \
  { _Pragma("unroll")                                                       \
    for (int i=0;i<2;i++){                                                  \
      int g=(i<<9)+t; int r=g>>4, c8=g&15;                                  \
      const float* p = in + (size_t)(row0+r)*DM + (kc)*128 + c8*8;          \
      float4 f0=*(const float4*)p, f1=*(const float4*)(p+4);                \
      rA[i][0]=f0.x; rA[i][1]=f0.y; rA[i][2]=f0.z; rA[i][3]=f0.w;           \
      rA[i][4]=f1.x; rA[i][5]=f1.y; rA[i][6]=f1.z; rA[i][7]=f1.w;           \
      if (r < KT){                                                          \
        const float* q2 = W + (size_t)r*DM + (kc)*128 + c8*8;               \
        float4 g0=*(const float4*)q2, g1=*(const float4*)(q2+4);            \
        rB[i][0]=g0.x; rB[i][1]=g0.y; rB[i][2]=g0.z; rB[i][3]=g0.w;         \
        rB[i][4]=g1.x; rB[i][5]=g1.y; rB[i][6]=g1.z; rB[i][7]=g1.w;         \
      } else {                                                              \
        _Pragma("unroll") for (int z=0;z<8;z++) rB[i][z]=0.f;               \
      }                                                                     \
    } }
#define WRITECHUNK(d)                                                       \
  { _Pragma("unroll")                                                       \
    for (int i=0;i<2;i++){                                                  \
      int g=(i<<9)+t; int r=g>>4, c8=g&15;                                  \
      int off = r*128 + ((c8*8) ^ ((r&7)<<3));                              \
      int4 da; da.x=pk2(rA[i][0],rA[i][1]); da.y=pk2(rA[i][2],rA[i][3]);    \
      da.z=pk2(rA[i][4],rA[i][5]); da.w=pk2(rA[i][6],rA[i][7]);             \
      *(int4*)(bA + (d)*8192 + off) = da;                                   \
      int4 db; db.x=pk2(rB[i][0],rB[i][1]); db.y=pk2(rB[i][2],rB[i][3]);    \
      db.z=pk2(rB[i][4],rB[i][5]); db.w=pk2(rB[i][6],rB[i][7]);             \
      *(int4*)(bB + (d)*8192 + off) = db;                                   \
    } }

  LOADCHUNK(0); WRITECHUNK(0);
  __syncthreads();
  for (int kc=0; kc<16; ++kc){
    const int d = kc & 1;
    if (kc < 15) LOADCHUNK(kc+1);
    const u16* Arow = bA + d*8192 + (32*rh + j0)*128;
    const u16* Brow = bB + d*8192 + (32*ch + j0)*128;
#pragma unroll
    for (int kk=0;kk<4;kk++){
      const int kt = kq*4 + kk;
      b16x8 aF = cast8(*(const int4*)(Arow + ((kt*16 + h*8) ^ aswz)));
      b16x8 bF = cast8(*(const int4*)(Brow + ((kt*16 + h*8) ^ aswz)));
      acc = mfma_(aF, bF, acc);
    }
    if (kc < 15) WRITECHUNK(d^1);
    __syncthreads();
  }
#undef LOADCHUNK
#undef WRITECHUNK

  // epilogue (LDS reuse is safe: loop ended with a barrier)
  float* planes = (float*)smem;            // [2][64][64]
  float* tile   = (float*)(smem + 32768);  // [64][66]
  float* mrow   = (float*)(smem + 49664);  // [64]
#pragma unroll
  for (int r=0;r<16;r++){
    int gp = (r&3) + 8*(r>>2) + 4*h;
    planes[kq*4096 + (32*rh + gp)*64 + 32*ch + j0] = acc[r];
  }
  __syncthreads();
  for (int cidx = t; cidx < 4096; cidx += 512){
    int g = cidx>>6, c = cidx&63;
    float v = planes[cidx] + planes[4096 + cidx];
    tile[g*66+c] = (c<KT) ? (v + bias[c]) : -1e4f;
  }
  __syncthreads();
  if (t < 64){
    int g = t;
    float mx = -1e30f;
    for (int c=0;c<KT;c++) mx = fmaxf(mx, tile[g*66+c]);
    mrow[g] = mx;
    int tt = row0 + g;
    int s1 = tags[tt];
    int s0 = (tt==0) ? NST : tags[tt-1];
    float part = (tile[g*66 + s1] - mx) + T[s1*50 + s0];
    if (tt == SEQ-1) part += T[NSP*50 + s1];
#pragma unroll
    for (int o=32;o>=1;o>>=1) part += __shfl_xor(part, o, 64);
    if (t==0) gpart[blockIdx.x] = part;
  }
  __syncthreads();
  for (int cidx = t; cidx < 4096; cidx += 512){
    int g = cidx>>6, c = cidx&63;
    feats[(size_t)(row0+g)*64 + c] = (c<KT) ? (tile[g*66+c] - mrow[g]) : -1e4f;
  }
}

// ============ kernel 2: scan (16 steps/wave) + tree + last-block finale ======
__global__ __launch_bounds__(512, 2) void k_scan(const float* __restrict__ feats,
        const float* __restrict__ T, const float* __restrict__ gpart,
        int* __restrict__ counter, u16* __restrict__ M1, float* __restrict__ S1,
        float* __restrict__ out){
  const int t = threadIdx.x;
  const int w = t>>6, lane = t&63;
  const int h = lane>>5;
  const int blk = blockIdx.x;
  __shared__ __align__(16) u16 E_lds[4096];
  __shared__ __align__(16) float u_lds[8][64];
  __shared__ __align__(16) u16 mats[8][4096];
  __shared__ float logs[8];
  __shared__ float alpha[64];
  __shared__ int bcast;

  // build E' = Pi*exp(T) swizzled in LDS
  for (int idx = t; idx < 4096; idx += 512){
    int a = idx>>6, b = idx&63;
    int pa = perm64(a);
    float v = (pa<KT && b<KT) ? __expf(T[pa*50 + b]) : 0.f;
    E_lds[a*64 + (b ^ ((a&7)<<3))] = bfb(v);
  }
  __syncthreads();

  b16x8 Af[2][4];
  load_afrag_lds(E_lds, Af, lane);
  b16x8 Bf[4][2];
  ident_frags<0>(Bf, lane);
  const int pl = perm64(lane);
  const int t0 = (blk*8 + w)*16;
  float x = feats[(size_t)t0*64 + pl];
  f32x16 acc[2][2];
#pragma unroll
  for (int s=0;s<16;s++){
    u_lds[w][lane] = __expf(x);
    if (s<15) x = feats[(size_t)(t0+s+1)*64 + pl];
    mm64(Af, Bf, acc);
    float uu0[16], uu1[16];
#pragma unroll
    for (int k2=0;k2<4;k2++){
      float4 v0 = *(const float4*)&u_lds[w][      8*k2 + 4*h];
      float4 v1 = *(const float4*)&u_lds[w][32 +  8*k2 + 4*h];
      uu0[4*k2+0]=v0.x; uu0[4*k2+1]=v0.y; uu0[4*k2+2]=v0.z; uu0[4*k2+3]=v0.w;
      uu1[4*k2+0]=v1.x; uu1[4*k2+1]=v1.y; uu1[4*k2+2]=v1.z; uu1[4*k2+3]=v1.w;
    }
#pragma unroll
    for (int ni=0;ni<2;ni++)
#pragma unroll
      for (int r=0;r<16;r++){
        acc[0][ni][r] *= uu0[r];
        acc[1][ni][r] *= uu1[r];
      }
    repack(acc, Bf);
  }
  float m = acc_wave_max(acc);
  store_mat_lds<1>(mats[w], acc, 1.0f/m, lane);
  if (lane==0) logs[w] = __logf(m);
  __syncthreads();
  if (w==0){
    float slog = logs[0]+logs[1]+logs[2]+logs[3]+logs[4]+logs[5]+logs[6]+logs[7];
    b16x8 Bc[4][2]; ident_frags<1>(Bc, lane);
    f32x16 a2[2][2];
#pragma unroll 1
    for (int m8=0;m8<8;m8++){
      b16x8 Am[2][4];
      load_afrag_lds(mats[m8], Am, lane);
      mm64(Am, Bc, a2);
      repack(a2, Bc);
    }
    float m2 = acc_wave_max(a2);
    slog += __logf(m2);
    store_mat_glob<0>(M1 + (size_t)blk*4096, a2, 1.0f/m2, lane);
    if (lane==0) S1[blk] = slog;
  }
  __syncthreads();
  if (t==0){
    __threadfence();                       // release M1/S1 to device scope
    bcast = atomicAdd(counter, 1);
  }
  __syncthreads();
  if (bcast != gridDim.x - 1) return;      // only the LAST block continues
  __threadfence();                         // acquire: invalidate stale caches

  // ---- stage 1: 8 waves x 16 mats each (prefetched chain, renorm at mid) ----
  {
    b16x8 Bc[4][2]; ident_frags<1>(Bc, lane);
    f32x16 a2[2][2];
    float sl = 0.f;
    b16x8 Acur[2][4], Anx[2][4];
    load_afrag_glob(M1 + (size_t)(w*16)*4096, Acur, lane);
#pragma unroll 1
    for (int mm=0; mm<16; mm++){
      if (mm<15) load_afrag_glob(M1 + (size_t)(w*16+mm+1)*4096, Anx, lane);
      sl += S1[w*16+mm];
      mm64(Acur, Bc, a2);
      if (mm==7){
        float mx = acc_wave_max(a2);
        sl += __logf(mx);
        repack_s(a2, Bc, 1.0f/mx);
      } else {
        repack(a2, Bc);
      }
#pragma unroll
      for (int mi=0;mi<2;mi++)
#pragma unroll
        for (int kt=0;kt<4;kt++) Acur[mi][kt] = Anx[mi][kt];
    }
    float mx = acc_wave_max(a2);
    sl += __logf(mx);
    store_mat_lds<0>(mats[w], a2, 1.0f/mx, lane);
    if (lane==0) logs[w] = sl;
  }
  __syncthreads();
  // ---- stage 2: wave 0 combines 8, extracts alpha, LSE, gold, output -------
  if (w==0){
    b16x8 Bc[4][2]; ident_frags<1>(Bc, lane);
    f32x16 a2[2][2];
#pragma unroll 1
    for (int m8=0;m8<8;m8++){
      b16x8 Am[2][4];
      load_afrag_lds(mats[m8], Am, lane);
      mm64(Am, Bc, a2);
      repack(a2, Bc);
    }
    float slog = logs[0]+logs[1]+logs[2]+logs[3]+logs[4]+logs[5]+logs[6]+logs[7];
    if ((lane&31)==16){   // column START=48 lives in lanes 16 / 48 (ni=1)
#pragma unroll
      for (int mi=0;mi<2;mi++)
#pragma unroll
        for (int r=0;r<16;r++){
          int gp = 32*mi + (r&3) + 8*(r>>2) + 4*h;
          alpha[gp] = a2[mi][1][r];
        }
    }
    float gold = gpart[lane] + gpart[lane+64] + gpart[lane+128] + gpart[lane+192];
#pragma unroll
    for (int o=32;o>=1;o>>=1) gold += __shfl_xor(gold, o, 64);
    float a = alpha[lane];
    float term = (lane < KT && a > 0.f) ? (__logf(a) + slog + T[NSP*50 + lane]) : -1e30f;
    float tm = term;
#pragma unroll
    for (int o=32;o>=1;o>>=1) tm = fmaxf(tm, __shfl_xor(tm, o, 64));
    float e = __expf(term - tm);
#pragma unroll
    for (int o=32;o>=1;o>>=1) e += __shfl_xor(e, o, 64);
    if (lane==0) out[0] = (tm + __logf(e)) - gold;
  }
}

extern "C" void kernel_launch(void* const* d_in, const int* in_sizes, int n_in,
                              void* d_out, int out_size, void* d_ws, size_t ws_size,
                              hipStream_t stream) {
  (void)in_sizes; (void)n_in; (void)out_size; (void)ws_size;
  const float* input = (const float*)d_in[0];
  const int*   tags  = (const int*)  d_in[1];
  const float* W     = (const float*)d_in[2];
  const float* bias  = (const float*)d_in[3];
  const float* T     = (const float*)d_in[4];

  char* ws = (char*)d_ws;
  float* feats   = (float*)(ws + 0);        // 16384*64*4 = 4194304
  float* gpart   = (float*)(ws + 4194304);  // 256*4      = 1024
  int*   counter = (int*)  (ws + 4195328);  // 4 (re-zeroed by k_gemm each call)
  u16*   M1      = (u16*)  (ws + 4195840);  // 128*4096*2 = 1048576
  float* S1      = (float*)(ws + 5244416);  // 128*4

  k_gemm<<<256, 512, 0, stream>>>(input, tags, W, bias, T, feats, gpart, counter);
  k_scan<<<128, 512, 0, stream>>>(feats, T, gpart, counter, M1, S1, (float*)d_out);
}